// Round 5
// baseline (249.125 us; speedup 1.0000x reference)
//
#include <hip/hip_runtime.h>
#include <hip/hip_bf16.h>

// E3TAOBackflow on MI355X — MFMA bf16, register-resident norms/gating.
// Reduction (verified R2+): antisymmetrization => scalar out = 0 exactly,
// vector out = (v @ [Wh0@Wu0]) * sigmoid([s,||v@Wh0||] @ Wm0 + bm0) @ C,
// C = Wh1@Wu1@W1/sqrt(S).  Wm1, bm1, W0 dead.  Output f32.
// R4: v1 overlays xv (LDS 21504 B, 5 blocks/CU), gate GEMM split around B2,
// zero-stores hoisted to kernel start, single prep kernel.

typedef __attribute__((ext_vector_type(8))) short short8;
typedef __attribute__((ext_vector_type(4))) float floatx4;

static __device__ __forceinline__ unsigned short f2bf(float f) {
  unsigned u = __float_as_uint(f);
  u = (u + 0x7fffu + ((u >> 16) & 1u)) >> 16;  // RNE
  return (unsigned short)u;
}
static __device__ __forceinline__ unsigned pk2(float lo, float hi) {
  __hip_bfloat162 h = __float22bfloat162_rn(make_float2(lo, hi));
  return *(unsigned*)&h;  // low 16 = lo
}

// write element B[k][n] into swizzled fragment layout (KT = K/32)
static __device__ __forceinline__ void put_sw(unsigned short* B, int k, int n,
                                              float val, int KT) {
  int kt = k >> 5, quad = (k >> 3) & 3, j = k & 7;
  int nt = n >> 4, c = n & 15;
  int lane = quad * 16 + c;
  B[(((nt * KT + kt) * 64 + lane) << 3) + j] = f2bf(val);
}

// ---- single prep kernel: grid 288 x 128
// b<128: Wcat_sw row m = [Wh0 row | (Wh0@Wu0) row]
// 128<=b<256: C_sw row m = ((Wh1@Wu1)@W1)[m] / sqrt(S)
// b>=256: Wm0_sw (32 blocks x 8 rows x 128 cols)
__global__ __launch_bounds__(128) void prep(
    const float* __restrict__ Wh0, const float* __restrict__ Wu0,
    const float* __restrict__ Wh1, const float* __restrict__ Wu1,
    const float* __restrict__ W1, const float* __restrict__ Wm0,
    unsigned short* __restrict__ Wcat_sw, unsigned short* __restrict__ C_sw,
    unsigned short* __restrict__ Wm0_sw) {
  __shared__ float trow[128];
  int b = blockIdx.x, tid = threadIdx.x;
  if (b < 128) {
    int m = b, o = tid;
    float acc = 0.f;
    for (int h = 0; h < 128; ++h) acc += Wh0[m * 128 + h] * Wu0[h * 128 + o];
    put_sw(Wcat_sw, m, o, Wh0[m * 128 + o], 4);
    put_sw(Wcat_sw, m, o + 128, acc, 4);
  } else if (b < 256) {
    int m = b - 128, o = tid;
    float acc = 0.f;
    for (int p = 0; p < 128; ++p) acc += Wh1[m * 128 + p] * Wu1[p * 128 + o];
    trow[o] = acc;
    __syncthreads();
#pragma unroll
    for (int nn = 0; nn < 2; ++nn) {
      int n = tid + 128 * nn;
      float c = 0.f;
      for (int h = 0; h < 128; ++h) c += trow[h] * W1[h * 256 + n];
      put_sw(C_sw, m, n, c * 0.08838834764831845f, 4);
    }
  } else {
    int kb = (b - 256) * 8;
#pragma unroll
    for (int kk = 0; kk < 8; ++kk)
      put_sw(Wm0_sw, kb + kk, tid, Wm0[(kb + kk) * 128 + tid], 8);
  }
}

#define XA_S 264   // bf16 row stride for xa (256 + 8 pad)
#define XV_S 136   // bf16 row stride for xv/v1 (128 + 8 pad)
#define XV_T 2176  // elements per t-plane (16 * 136)

__global__ __launch_bounds__(256, 5) void main_k(
    const float* __restrict__ x, const float* __restrict__ bm0,
    const unsigned short* __restrict__ Wcat_sw,
    const unsigned short* __restrict__ Wm0_sw,
    const unsigned short* __restrict__ C_sw, float* __restrict__ out) {
  // LDS (21504 B): xa [0,8448) | xv [8448,21504).  v1 overlays xv (xv is
  // dead after phase1, which finishes before B2; gating writes after B2).
  __shared__ __align__(16) unsigned char smem[21504];
  unsigned short* xa = (unsigned short*)smem;
  unsigned short* xv = (unsigned short*)(smem + 8448);
  unsigned short* v1 = xv;

  const int tid = threadIdx.x;
  const int lane = tid & 63;
  const int w = tid >> 6;
  const int l15 = lane & 15;
  const int quad = lane >> 4;
  const int r0 = blockIdx.x << 4;  // 16 rows/block
  const float* xrow = x + (size_t)r0 * 512;
  float* orow = out + (size_t)r0 * 1024;
  const int ntg[4] = {2 * w, 2 * w + 1, 8 + 2 * w, 9 + 2 * w};

  // ---- zero-stores first: independent of all compute, drain in background.
  // Row layout: 16 groups of 64 floats = [16 zeros | 48 data].
#pragma unroll
  for (int i = 0; i < 4; ++i) {
    int e = tid + 256 * i;
    int r = e >> 6, gblk = (e >> 2) & 15, s4 = e & 3;
    *(float4*)(orow + (size_t)r * 1024 + gblk * 64 + s4 * 4) =
        make_float4(0.f, 0.f, 0.f, 0.f);
  }

  // bias for the gate cols this lane owns
  float bias0 = bm0[(2 * w) * 16 + l15];
  float bias1 = bm0[(2 * w + 1) * 16 + l15];

  // ---- stage: s -> xa bf16; v -> xv[t][r][m] bf16 (packed b64 writes)
#pragma unroll
  for (int i = 0; i < 2; ++i) {  // s: 512 float4 chunks
    int e = tid + 256 * i;
    int r = e >> 5, c0 = (e & 31) << 2;
    float4 s4 = *(const float4*)(xrow + r * 512 + c0);
    *(uint2*)(xa + r * XA_S + c0) = make_uint2(pk2(s4.x, s4.y), pk2(s4.z, s4.w));
  }
#pragma unroll
  for (int i = 0; i < 2; ++i) {  // v: 512 chunks of 12 floats (4 m x 3 t)
    int e = tid + 256 * i;
    int r = e >> 5, mc = e & 31;
    const float* p = xrow + r * 512 + 128 + mc * 12;
    float4 a = *(const float4*)(p);
    float4 b = *(const float4*)(p + 4);
    float4 c = *(const float4*)(p + 8);
    float f[12] = {a.x, a.y, a.z, a.w, b.x, b.y, b.z, b.w, c.x, c.y, c.z, c.w};
#pragma unroll
    for (int t = 0; t < 3; ++t)
      *(uint2*)(xv + t * XV_T + r * XV_S + mc * 4) =
          make_uint2(pk2(f[t], f[t + 3]), pk2(f[t + 6], f[t + 9]));
  }
  __syncthreads();  // B1

  const floatx4 zf4 = {0.f, 0.f, 0.f, 0.f};

  // ---- phase1: per t, [Vh|Vu](16x256) = xv_t(16x128) @ Wcat; B shared over t
  floatx4 acc[3][4];
#pragma unroll
  for (int t = 0; t < 3; ++t)
#pragma unroll
    for (int j = 0; j < 4; ++j) acc[t][j] = zf4;
  for (int kt = 0; kt < 4; ++kt) {
    short8 bf[4];
#pragma unroll
    for (int j = 0; j < 4; ++j)
      bf[j] = *(const short8*)(Wcat_sw + (((ntg[j] * 4 + kt) * 64 + lane) << 3));
#pragma unroll
    for (int t = 0; t < 3; ++t) {
      short8 af = *(const short8*)(xv + t * XV_T + l15 * XV_S + kt * 32 + quad * 8);
#pragma unroll
      for (int j = 0; j < 4; ++j)
        acc[t][j] = __builtin_amdgcn_mfma_f32_16x16x32_bf16(af, bf[j], acc[t][j], 0, 0, 0);
    }
  }

  // ---- norms in registers: vn = sqrt(sum_t Vh_t^2 + eps) -> xa[:,128:]
#pragma unroll
  for (int j = 0; j < 2; ++j)
#pragma unroll
    for (int rg = 0; rg < 4; ++rg) {
      float s0 = acc[0][j][rg], s1 = acc[1][j][rg], s2 = acc[2][j][rg];
      float vn = sqrtf(s0 * s0 + s1 * s1 + s2 * s2 + 1e-8f);
      xa[(quad * 4 + rg) * XA_S + 128 + ntg[j] * 16 + l15] = f2bf(vn);
    }

  // ---- gate GEMM, s-half (kt 0..3, reads xa[:,:128] valid since B1)
  floatx4 ga[2] = {zf4, zf4};
  for (int kt = 0; kt < 4; ++kt) {
    short8 af = *(const short8*)(xa + l15 * XA_S + kt * 32 + quad * 8);
    short8 b0 = *(const short8*)(Wm0_sw + ((((2 * w) * 8 + kt) * 64 + lane) << 3));
    short8 b1 = *(const short8*)(Wm0_sw + ((((2 * w + 1) * 8 + kt) * 64 + lane) << 3));
    ga[0] = __builtin_amdgcn_mfma_f32_16x16x32_bf16(af, b0, ga[0], 0, 0, 0);
    ga[1] = __builtin_amdgcn_mfma_f32_16x16x32_bf16(af, b1, ga[1], 0, 0, 0);
  }
  __syncthreads();  // B2 (vn writes visible)

  // ---- gate GEMM, vn-half (kt 4..7)
  for (int kt = 4; kt < 8; ++kt) {
    short8 af = *(const short8*)(xa + l15 * XA_S + kt * 32 + quad * 8);
    short8 b0 = *(const short8*)(Wm0_sw + ((((2 * w) * 8 + kt) * 64 + lane) << 3));
    short8 b1 = *(const short8*)(Wm0_sw + ((((2 * w + 1) * 8 + kt) * 64 + lane) << 3));
    ga[0] = __builtin_amdgcn_mfma_f32_16x16x32_bf16(af, b0, ga[0], 0, 0, 0);
    ga[1] = __builtin_amdgcn_mfma_f32_16x16x32_bf16(af, b1, ga[1], 0, 0, 0);
  }

  // sigmoid + gating in registers (gate D-layout == Vu acc layout, lane-exact);
  // v1 overlays xv — xv globally dead after B2.
  float g[2][4];
#pragma unroll
  for (int j = 0; j < 2; ++j) {
    float bias = j ? bias1 : bias0;
#pragma unroll
    for (int rg = 0; rg < 4; ++rg)
      g[j][rg] = 1.f / (1.f + __expf(-(ga[j][rg] + bias)));
  }
#pragma unroll
  for (int t = 0; t < 3; ++t)
#pragma unroll
    for (int j = 0; j < 2; ++j)
#pragma unroll
      for (int rg = 0; rg < 4; ++rg)
        v1[t * XV_T + (quad * 4 + rg) * XV_S + (2 * w + j) * 16 + l15] =
            f2bf(acc[t][2 + j][rg] * g[j][rg]);
  __syncthreads();  // B3

  // ---- phase3: per t, vo_t(16x256) = v1_t(16x128) @ C; B shared over t
  floatx4 vacc[3][4];
#pragma unroll
  for (int t = 0; t < 3; ++t)
#pragma unroll
    for (int j = 0; j < 4; ++j) vacc[t][j] = zf4;
  for (int kt = 0; kt < 4; ++kt) {
    short8 bf[4];
#pragma unroll
    for (int j = 0; j < 4; ++j)
      bf[j] = *(const short8*)(C_sw + (((ntg[j] * 4 + kt) * 64 + lane) << 3));
#pragma unroll
    for (int t = 0; t < 3; ++t) {
      short8 af = *(const short8*)(v1 + t * XV_T + l15 * XV_S + kt * 32 + quad * 8);
#pragma unroll
      for (int j = 0; j < 4; ++j)
        vacc[t][j] = __builtin_amdgcn_mfma_f32_16x16x32_bf16(af, bf[j], vacc[t][j], 0, 0, 0);
    }
  }

  // ---- data stores: out col = nt*64 + 16 + 3*l15 + t, row = quad*4+rg
#pragma unroll
  for (int j = 0; j < 4; ++j) {
    int nt = ntg[j];
#pragma unroll
    for (int rg = 0; rg < 4; ++rg) {
      int r = quad * 4 + rg;
      *(float3*)(orow + (size_t)r * 1024 + nt * 64 + 16 + 3 * l15) =
          make_float3(vacc[0][j][rg], vacc[1][j][rg], vacc[2][j][rg]);
    }
  }
}

extern "C" void kernel_launch(void* const* d_in, const int* in_sizes, int n_in,
                              void* d_out, int out_size, void* d_ws,
                              size_t ws_size, hipStream_t stream) {
  const float* mo = (const float*)d_in[0];
  const float* Wh0 = (const float*)d_in[1];
  const float* Wu0 = (const float*)d_in[2];
  const float* Wm0 = (const float*)d_in[3];
  const float* bm0 = (const float*)d_in[4];
  const float* Wh1 = (const float*)d_in[5];
  const float* Wu1 = (const float*)d_in[6];
  const float* W1 = (const float*)d_in[10];
  // d_in[7]=Wm1, d_in[8]=bm1, d_in[9]=W0: dead under antisymmetrization

  unsigned short* ws = (unsigned short*)d_ws;
  unsigned short* Wcat_sw = ws;         // 64 KB
  unsigned short* C_sw = ws + 32768;    // 64 KB
  unsigned short* Wm0_sw = ws + 65536;  // 64 KB

  prep<<<288, 128, 0, stream>>>(Wh0, Wu0, Wh1, Wu1, W1, Wm0, Wcat_sw, C_sw,
                                Wm0_sw);
  main_k<<<2048, 256, 0, stream>>>(mo, bm0, Wcat_sw, Wm0_sw, C_sw,
                                   (float*)d_out);
}